// Round 8
// baseline (142.970 us; speedup 1.0000x reference)
//
#include <hip/hip_runtime.h>

typedef unsigned short u16;
typedef unsigned int   u32;
typedef __attribute__((ext_vector_type(8)))  short short8;
typedef __attribute__((ext_vector_type(4)))  float f32x4;
typedef __attribute__((ext_vector_type(16))) float f32x16;
typedef __attribute__((ext_vector_type(2)))  u32 uint2v;
typedef __attribute__((ext_vector_type(4)))  u32 uint4v;

#define DEV __device__ __forceinline__

DEV u16 f2bf(float f) {
    u32 u = __builtin_bit_cast(u32, f);
    return (u16)((u + 0x7fffu + ((u >> 16) & 1u)) >> 16);
}
DEV float bf2f(u32 u) { return __builtin_bit_cast(float, u << 16); }
DEV u32 cvtpk(float a, float b) {
    u32 r;
    asm("v_cvt_pk_bf16_f32 %0, %1, %2" : "=v"(r) : "v"(a), "v"(b));
    return r;
}
typedef const __attribute__((address_space(1))) u32 g_u32;
typedef __attribute__((address_space(3))) u32 l_u32;
DEV void gload16(const u16* g, u16* l) {
    __builtin_amdgcn_global_load_lds((g_u32*)g, (l_u32*)l, 16, 0, 0);
}

// ---------------------------------------------------------------------------
// Packed K layout (per bh, per 32-token tile, 4KB): elem index
//   ((c*2+hi)*32 + lo)*8 + e  holds  K[t=tblk*32+lo][d=c*16+hi*8+e]
// => fragment kf[c] = 16B at tile + (c*64+lane)*16B, fully linear.
// Packed V layout (per bh, per 32-token tile, 4KB): elem index
//   ((kc*2+c2)*64 + hi*32 + lo)*8 + e holds V[t=tblk*32+kc*16+hi*8+e][d=c2*32+lo]
// => fragment vf[kc*2+c2] = 16B at tile + ((kc*2+c2)*64+lane)*16B.
// ---------------------------------------------------------------------------

// GEMM: C[4096,1024] = A[4096,1024](bf16) @ Wt[n][k](bf16) + bias.
// 128x128 tile, BK=32, 256 thr (4 waves 2x2), 16x16x32 MFMA, m97 staging.
// OMODE 0: bf16 row-major (*oscale); 1: packed-V tiles; 2: f32 row-major;
//   3: packed-K tiles.
template<int OMODE>
DEV void gemm_body(const u16* __restrict__ A_, const u16* __restrict__ Bt,
                   const float* __restrict__ bias, float oscale, void* C_) {
    constexpr int Kd = 1024;
    const int m0 = blockIdx.y * 128, n0 = blockIdx.x * 128;
    const int t = threadIdx.x, lane = t & 63, w = t >> 6;
    const int wm = w >> 1, wn = w & 1;
    const int l15 = lane & 15, l4 = lane >> 4;
    __shared__ __align__(16) u16 As[128 * 32];
    __shared__ __align__(16) u16 Bs[128 * 32];
    f32x4 acc[4][4] = {};

    for (int k0 = 0; k0 < Kd; k0 += 32) {
        #pragma unroll
        for (int rnd = 0; rnd < 2; rnd++) {
            int cc = rnd * 256 + t, row = cc >> 2, slot = cc & 3;
            gload16(Bt + (size_t)(n0 + row) * Kd + k0 + slot * 8, Bs + cc * 8);
            gload16(A_ + (size_t)(m0 + row) * Kd + k0 + slot * 8, As + cc * 8);
        }
        __syncthreads();
        short8 af[4], bfr[4];
        #pragma unroll
        for (int i = 0; i < 4; i++) {
            af[i]  = *(const short8*)(As + (wm * 64 + i * 16 + l15) * 32 + l4 * 8);
            bfr[i] = *(const short8*)(Bs + (wn * 64 + i * 16 + l15) * 32 + l4 * 8);
        }
        #pragma unroll
        for (int i = 0; i < 4; i++)
            #pragma unroll
            for (int j = 0; j < 4; j++)
                acc[i][j] = __builtin_amdgcn_mfma_f32_16x16x32_bf16(af[i], bfr[j], acc[i][j], 0, 0, 0);
        __syncthreads();
    }

    #pragma unroll
    for (int i = 0; i < 4; i++) {
        #pragma unroll
        for (int j = 0; j < 4; j++) {
            int col = n0 + wn * 64 + j * 16 + l15;
            int mb  = m0 + wm * 64 + i * 16 + l4 * 4;
            float bv = bias[col];
            if (OMODE == 2) {
                float* C = (float*)C_;
                #pragma unroll
                for (int r = 0; r < 4; r++)
                    C[(size_t)(mb + r) * 1024 + col] = acc[i][j][r] + bv;
            } else if (OMODE == 0) {
                u16* C = (u16*)C_;
                #pragma unroll
                for (int r = 0; r < 4; r++)
                    C[(size_t)(mb + r) * 1024 + col] = f2bf((acc[i][j][r] + bv) * oscale);
            } else if (OMODE == 3) {
                // packed K tiles
                u16* C = (u16*)C_;
                int hh = col >> 6, dd = col & 63;
                int bb = mb >> 11, tt = mb & 2047;
                size_t tile = ((size_t)(bb * 16 + hh) * 64 + (tt >> 5)) * 2048;
                int c = dd >> 4, hi2 = (dd >> 3) & 1, e = dd & 7;
                int lob = tt & 31;
                #pragma unroll
                for (int r = 0; r < 4; r++)
                    C[tile + (size_t)((c * 2 + hi2) * 32 + lob + r) * 8 + e] =
                        f2bf(acc[i][j][r] + bv);
            } else {
                // packed V tiles: 4 consecutive tokens are contiguous elems
                u16* C = (u16*)C_;
                int hh = col >> 6, dd = col & 63;
                int bb = mb >> 11, tt = mb & 2047;
                size_t tile = ((size_t)(bb * 16 + hh) * 64 + (tt >> 5)) * 2048;
                int tin = tt & 31, kc = tin >> 4, hi2 = (tin >> 3) & 1, e0 = tin & 7;
                int c2 = dd >> 5, lo2 = dd & 31;
                size_t off = tile + (size_t)((kc * 2 + c2) * 64 + hi2 * 32 + lo2) * 8 + e0;
                uint2v pp;
                pp[0] = cvtpk(acc[i][j][0] + bv, acc[i][j][1] + bv);
                pp[1] = cvtpk(acc[i][j][2] + bv, acc[i][j][3] + bv);
                *(uint2v*)(C + off) = pp;
            }
        }
    }
}

// weights: W[k][n] f32 -> Wt[n][k] bf16
__global__ __launch_bounds__(256) void k_transw(const float* Wq, const float* Wk,
                                                const float* Wv, const float* Wo, u16* Wt) {
    int z = blockIdx.z;
    const float* W = z == 0 ? Wq : z == 1 ? Wk : z == 2 ? Wv : Wo;
    u16* O = Wt + (size_t)z * 1048576;
    __shared__ float tile[32][33];
    int n0 = blockIdx.x * 32, k0 = blockIdx.y * 32;
    int tx = threadIdx.x, ty = threadIdx.y;
    #pragma unroll
    for (int i = 0; i < 32; i += 8) tile[ty + i][tx] = W[(size_t)(k0 + ty + i) * 1024 + n0 + tx];
    __syncthreads();
    #pragma unroll
    for (int i = 0; i < 32; i += 8) O[(size_t)(n0 + ty + i) * 1024 + k0 + tx] = f2bf(tile[tx][ty + i]);
}

// q,k,v f32 -> bf16, fully coalesced, 8 elems/thread, exact coverage
__global__ __launch_bounds__(256) void k_cvt(const float* q, const float* k, const float* v,
                                             u16* Abf) {
    int z = blockIdx.z;
    const float* src = z == 0 ? q : z == 1 ? k : v;
    u16* dst = Abf + (size_t)z * 4194304;
    size_t i = ((size_t)blockIdx.x * 256 + threadIdx.x) * 8;
    float4 a = *(const float4*)(src + i);
    float4 b = *(const float4*)(src + i + 4);
    uint4v o;
    o[0] = cvtpk(a.x, a.y); o[1] = cvtpk(a.z, a.w);
    o[2] = cvtpk(b.x, b.y); o[3] = cvtpk(b.z, b.w);
    *(uint4v*)(dst + i) = o;
}

__global__ __launch_bounds__(256) void k_proj(const u16* Abf, const u16* Wt,
                                              const float* bq, const float* bk,
                                              const float* bv, u16* QKV) {
    int z = blockIdx.z;
    if (z == 2)
        gemm_body<1>(Abf + (size_t)2 * 4194304, Wt + (size_t)2 * 1048576, bv, 1.f,
                     QKV + (size_t)2 * 4194304);
    else if (z == 1)
        gemm_body<3>(Abf + (size_t)4194304, Wt + (size_t)1048576, bk, 1.f,
                     QKV + (size_t)4194304);
    else   // softmax scale AND log2(e) folded into Q so attn uses exp2 directly
        gemm_body<0>(Abf, Wt, bq, 0.125f * 1.44269504088896f, QKV);
}

__global__ __launch_bounds__(256) void k_gemm_out(const u16* Xc, const u16* Wt,
                                                  const float* bo, float* out) {
    gemm_body<2>(Xc, Wt, bo, 1.f, out);
}

// ---------------------------------------------------------------------------
// Causal flash attention v3: LDS-shared K/V staging.
// grid (16, 32), 256 thr = 4 waves. Block x (j = 15-x, heavy-first) owns
// q-tiles {4j..4j+3}, one per wave. K/V packed tiles (4KB each) staged once
// per block into LDS (one gload16 round: 256 thr x 16B = 4KB), consumed by
// all 4 waves as ds_read_b128. One barrier per k-tile: stage(kt+1) issued
// right after the barrier that publishes stage(kt).
// No-max softmax (exp2, scale pre-folded), direct normalized bf16 output.
// ---------------------------------------------------------------------------
__global__ __launch_bounds__(256, 2) void k_attn(const u16* __restrict__ Qp,
                                                 const u16* __restrict__ Kp2,
                                                 const u16* __restrict__ Vp2,
                                                 u16* __restrict__ Xc) {
    const int bh = blockIdx.y, b = bh >> 4, h = bh & 15;
    const int t = threadIdx.x, lane = t & 63, w = t >> 6;
    const int lo = lane & 31, hi = lane >> 5;
    const int j = 15 - (int)blockIdx.x;        // heavy-first
    const int q0 = (j * 4 + w) * 32;           // this wave's q-tile
    const int NTw = j * 4 + w + 1;             // this wave's causal k-tiles
    const int NT  = j * 4 + 4;                 // block staging count
    const u16* Qb = Qp + (size_t)(b * 2048) * 1024 + h * 64;
    const u16* Kb = Kp2 + (size_t)bh * 64 * 2048;
    const u16* Vb = Vp2 + (size_t)bh * 64 * 2048;

    __shared__ __align__(16) u16 Ks[2][2048];
    __shared__ __align__(16) u16 Vs[2][2048];

    short8 qf[4];
    #pragma unroll
    for (int c = 0; c < 4; c++)
        qf[c] = *(const short8*)(Qb + (size_t)(q0 + lo) * 1024 + c * 16 + hi * 8);

    f32x16 O0 = {}, O1 = {};
    float lsum = 0.f;
    const int qg = q0 + lo;

    // one packed tile = 2048 u16 = 4KB; 256 threads x 16B covers it in ONE round
#define STAGE(buf, kt) do {                                                              \
        gload16(Kb + (size_t)(kt) * 2048 + t * 8, Ks[buf] + t * 8);                      \
        gload16(Vb + (size_t)(kt) * 2048 + t * 8, Vs[buf] + t * 8);                      \
    } while (0)

    STAGE(0, 0);
    for (int kt = 0; kt < NT; kt++) {
        __syncthreads();                       // publishes stage(kt); fences buf reuse
        if (kt + 1 < NT) STAGE((kt + 1) & 1, kt + 1);
        if (kt < NTw) {
            const u16* kl = Ks[kt & 1];
            const u16* vl = Vs[kt & 1];
            short8 kf[4], vf[4];
            #pragma unroll
            for (int c = 0; c < 4; c++) {
                kf[c] = *(const short8*)(kl + (c * 64 + lane) * 8);
                vf[c] = *(const short8*)(vl + (c * 64 + lane) * 8);
            }
            f32x16 S = {};
            #pragma unroll
            for (int c = 0; c < 4; c++)
                S = __builtin_amdgcn_mfma_f32_32x32x16_bf16(kf[c], qf[c], S, 0, 0, 0);
            const bool diag = (kt == NTw - 1);
            #pragma unroll
            for (int kc = 0; kc < 2; kc++) {
                float pv[8];
                #pragma unroll
                for (int jj = 0; jj < 8; jj++) {
                    int r = kc * 8 + jj;
                    float s = S[r];
                    if (diag) {
                        int kg = kt * 32 + (r & 3) + 8 * (r >> 2) + 4 * hi;
                        s = (kg <= qg) ? s : -1e30f;
                    }
                    pv[jj] = __builtin_amdgcn_exp2f(s);
                }
                lsum += (((pv[0] + pv[1]) + (pv[2] + pv[3])) +
                         ((pv[4] + pv[5]) + (pv[6] + pv[7])));
                u32 w0 = cvtpk(pv[0], pv[1]), w1 = cvtpk(pv[2], pv[3]);
                u32 w2 = cvtpk(pv[4], pv[5]), w3 = cvtpk(pv[6], pv[7]);
                auto r0 = __builtin_amdgcn_permlane32_swap(w0, w2, false, false);
                auto r1 = __builtin_amdgcn_permlane32_swap(w1, w3, false, false);
                uint4v fw; fw[0] = r0[0]; fw[1] = r1[0]; fw[2] = r0[1]; fw[3] = r1[1];
                short8 pf = __builtin_bit_cast(short8, fw);
                O0 = __builtin_amdgcn_mfma_f32_32x32x16_bf16(pf, vf[kc * 2 + 0], O0, 0, 0, 0);
                O1 = __builtin_amdgcn_mfma_f32_32x32x16_bf16(pf, vf[kc * 2 + 1], O1, 0, 0, 0);
            }
        }
    }
#undef STAGE

    float ltot = lsum + __shfl_xor(lsum, 32, 64);
    #pragma unroll
    for (int r = 0; r < 16; r++) {
        int qr = (r & 3) + 8 * (r >> 2) + 4 * hi;
        float lt = __shfl(ltot, qr, 64);       // normalizer of q-row qr
        float linv = lt > 0.f ? 1.f / lt : 0.f;
        size_t rowb = (size_t)(b * 2048 + q0 + qr) * 1024 + h * 64;
        Xc[rowb + lo]      = f2bf(O0[r] * linv);
        Xc[rowb + 32 + lo] = f2bf(O1[r] * linv);
    }
}

extern "C" void kernel_launch(void* const* d_in, const int* in_sizes, int n_in,
                              void* d_out, int out_size, void* d_ws, size_t ws_size,
                              hipStream_t stream) {
    (void)in_sizes; (void)n_in; (void)out_size; (void)ws_size;
    const float* q  = (const float*)d_in[0];
    const float* k  = (const float*)d_in[1];
    const float* v  = (const float*)d_in[2];
    const float* Wq = (const float*)d_in[3];
    const float* bq = (const float*)d_in[4];
    const float* Wk = (const float*)d_in[5];
    const float* bk = (const float*)d_in[6];
    const float* Wv = (const float*)d_in[7];
    const float* bv = (const float*)d_in[8];
    const float* Wo = (const float*)d_in[9];
    const float* bo = (const float*)d_in[10];

    // workspace layout (u16 units):
    //   [0, 4M)     Wt  : 4 x 1024x1024 bf16                 (8 MB)
    //   [4M, 16M)   QKV : Q row-major, K packed, V packed    (24 MB)
    //   [16M, 28M)  Abf : q,k,v bf16 (dead after k_proj)     (24 MB)
    //               reused: Xc = Abf[0:4M)
    u16* Wt  = (u16*)d_ws;
    u16* QKV = Wt + (size_t)4 * 1048576;
    u16* Abf = QKV + (size_t)3 * 4194304;
    u16* Xc  = Abf;                           // reuse (Abf dead after k_proj)

    k_transw<<<dim3(32, 32, 4), dim3(32, 8), 0, stream>>>(Wq, Wk, Wv, Wo, Wt);
    k_cvt<<<dim3(2048, 1, 3), 256, 0, stream>>>(q, k, v, Abf);
    k_proj<<<dim3(8, 32, 3), 256, 0, stream>>>(Abf, Wt, bq, bk, bv, QKV);
    k_attn<<<dim3(16, 32), 256, 0, stream>>>(QKV, QKV + (size_t)4194304,
                                             QKV + (size_t)2 * 4194304, Xc);
    k_gemm_out<<<dim3(8, 32), 256, 0, stream>>>(Xc, Wt + (size_t)3 * 1048576,
                                                bo, (float*)d_out);
}

// Round 10
// 136.473 us; speedup vs baseline: 1.0476x; 1.0476x over previous
//
#include <hip/hip_runtime.h>

typedef unsigned short u16;
typedef unsigned int   u32;
typedef __attribute__((ext_vector_type(8)))  short short8;
typedef __attribute__((ext_vector_type(4)))  float f32x4;
typedef __attribute__((ext_vector_type(16))) float f32x16;
typedef __attribute__((ext_vector_type(2)))  u32 uint2v;
typedef __attribute__((ext_vector_type(4)))  u32 uint4v;

#define DEV __device__ __forceinline__

DEV u16 f2bf(float f) {
    u32 u = __builtin_bit_cast(u32, f);
    return (u16)((u + 0x7fffu + ((u >> 16) & 1u)) >> 16);
}
DEV float bf2f(u32 u) { return __builtin_bit_cast(float, u << 16); }
DEV u32 cvtpk(float a, float b) {
    u32 r;
    asm("v_cvt_pk_bf16_f32 %0, %1, %2" : "=v"(r) : "v"(a), "v"(b));
    return r;
}
typedef const __attribute__((address_space(1))) u32 g_u32;
typedef __attribute__((address_space(3))) u32 l_u32;
DEV void gload16(const u16* g, u16* l) {
    __builtin_amdgcn_global_load_lds((g_u32*)g, (l_u32*)l, 16, 0, 0);
}

// ---------------------------------------------------------------------------
// Packed K layout (per bh, per 32-token tile, 4KB): elem index
//   ((c*2+hi)*32 + lo)*8 + e  holds  K[t=tblk*32+lo][d=c*16+hi*8+e]
// => fragment kf[c] = 16B at tile + (c*64+lane)*16B, fully linear.
// Packed V layout (per bh, per 32-token tile, 4KB): elem index
//   ((kc*2+c2)*64 + hi*32 + lo)*8 + e holds V[t=tblk*32+kc*16+hi*8+e][d=c2*32+lo]
// => fragment vf[kc*2+c2] = 16B at tile + ((kc*2+c2)*64+lane)*16B.
// ---------------------------------------------------------------------------

// GEMM: C[4096,1024] = A[4096,1024](bf16) @ Wt[n][k](bf16) + bias.
// 128x128 tile, BK=32, 256 thr (4 waves 2x2), 16x16x32 MFMA, m97 staging.
// OMODE 0: bf16 row-major (*oscale); 1: packed-V tiles; 2: f32 row-major;
//   3: packed-K tiles.
template<int OMODE>
DEV void gemm_body(const u16* __restrict__ A_, const u16* __restrict__ Bt,
                   const float* __restrict__ bias, float oscale, void* C_) {
    constexpr int Kd = 1024;
    const int m0 = blockIdx.y * 128, n0 = blockIdx.x * 128;
    const int t = threadIdx.x, lane = t & 63, w = t >> 6;
    const int wm = w >> 1, wn = w & 1;
    const int l15 = lane & 15, l4 = lane >> 4;
    __shared__ __align__(16) u16 As[128 * 32];
    __shared__ __align__(16) u16 Bs[128 * 32];
    f32x4 acc[4][4] = {};

    for (int k0 = 0; k0 < Kd; k0 += 32) {
        #pragma unroll
        for (int rnd = 0; rnd < 2; rnd++) {
            int cc = rnd * 256 + t, row = cc >> 2, slot = cc & 3;
            gload16(Bt + (size_t)(n0 + row) * Kd + k0 + slot * 8, Bs + cc * 8);
            gload16(A_ + (size_t)(m0 + row) * Kd + k0 + slot * 8, As + cc * 8);
        }
        __syncthreads();
        short8 af[4], bfr[4];
        #pragma unroll
        for (int i = 0; i < 4; i++) {
            af[i]  = *(const short8*)(As + (wm * 64 + i * 16 + l15) * 32 + l4 * 8);
            bfr[i] = *(const short8*)(Bs + (wn * 64 + i * 16 + l15) * 32 + l4 * 8);
        }
        #pragma unroll
        for (int i = 0; i < 4; i++)
            #pragma unroll
            for (int j = 0; j < 4; j++)
                acc[i][j] = __builtin_amdgcn_mfma_f32_16x16x32_bf16(af[i], bfr[j], acc[i][j], 0, 0, 0);
        __syncthreads();
    }

    #pragma unroll
    for (int i = 0; i < 4; i++) {
        #pragma unroll
        for (int j = 0; j < 4; j++) {
            int col = n0 + wn * 64 + j * 16 + l15;
            int mb  = m0 + wm * 64 + i * 16 + l4 * 4;
            float bv = bias[col];
            if (OMODE == 2) {
                float* C = (float*)C_;
                #pragma unroll
                for (int r = 0; r < 4; r++)
                    C[(size_t)(mb + r) * 1024 + col] = acc[i][j][r] + bv;
            } else if (OMODE == 0) {
                u16* C = (u16*)C_;
                #pragma unroll
                for (int r = 0; r < 4; r++)
                    C[(size_t)(mb + r) * 1024 + col] = f2bf((acc[i][j][r] + bv) * oscale);
            } else if (OMODE == 3) {
                // packed K tiles
                u16* C = (u16*)C_;
                int hh = col >> 6, dd = col & 63;
                int bb = mb >> 11, tt = mb & 2047;
                size_t tile = ((size_t)(bb * 16 + hh) * 64 + (tt >> 5)) * 2048;
                int c = dd >> 4, hi2 = (dd >> 3) & 1, e = dd & 7;
                int lob = tt & 31;
                #pragma unroll
                for (int r = 0; r < 4; r++)
                    C[tile + (size_t)((c * 2 + hi2) * 32 + lob + r) * 8 + e] =
                        f2bf(acc[i][j][r] + bv);
            } else {
                // packed V tiles: 4 consecutive tokens are contiguous elems
                u16* C = (u16*)C_;
                int hh = col >> 6, dd = col & 63;
                int bb = mb >> 11, tt = mb & 2047;
                size_t tile = ((size_t)(bb * 16 + hh) * 64 + (tt >> 5)) * 2048;
                int tin = tt & 31, kc = tin >> 4, hi2 = (tin >> 3) & 1, e0 = tin & 7;
                int c2 = dd >> 5, lo2 = dd & 31;
                size_t off = tile + (size_t)((kc * 2 + c2) * 64 + hi2 * 32 + lo2) * 8 + e0;
                uint2v pp;
                pp[0] = cvtpk(acc[i][j][0] + bv, acc[i][j][1] + bv);
                pp[1] = cvtpk(acc[i][j][2] + bv, acc[i][j][3] + bv);
                *(uint2v*)(C + off) = pp;
            }
        }
    }
}

// weights: W[k][n] f32 -> Wt[n][k] bf16
__global__ __launch_bounds__(256) void k_transw(const float* Wq, const float* Wk,
                                                const float* Wv, const float* Wo, u16* Wt) {
    int z = blockIdx.z;
    const float* W = z == 0 ? Wq : z == 1 ? Wk : z == 2 ? Wv : Wo;
    u16* O = Wt + (size_t)z * 1048576;
    __shared__ float tile[32][33];
    int n0 = blockIdx.x * 32, k0 = blockIdx.y * 32;
    int tx = threadIdx.x, ty = threadIdx.y;
    #pragma unroll
    for (int i = 0; i < 32; i += 8) tile[ty + i][tx] = W[(size_t)(k0 + ty + i) * 1024 + n0 + tx];
    __syncthreads();
    #pragma unroll
    for (int i = 0; i < 32; i += 8) O[(size_t)(n0 + ty + i) * 1024 + k0 + tx] = f2bf(tile[tx][ty + i]);
}

// q,k,v f32 -> bf16, fully coalesced, 8 elems/thread, exact coverage
__global__ __launch_bounds__(256) void k_cvt(const float* q, const float* k, const float* v,
                                             u16* Abf) {
    int z = blockIdx.z;
    const float* src = z == 0 ? q : z == 1 ? k : v;
    u16* dst = Abf + (size_t)z * 4194304;
    size_t i = ((size_t)blockIdx.x * 256 + threadIdx.x) * 8;
    float4 a = *(const float4*)(src + i);
    float4 b = *(const float4*)(src + i + 4);
    uint4v o;
    o[0] = cvtpk(a.x, a.y); o[1] = cvtpk(a.z, a.w);
    o[2] = cvtpk(b.x, b.y); o[3] = cvtpk(b.z, b.w);
    *(uint4v*)(dst + i) = o;
}

__global__ __launch_bounds__(256) void k_proj(const u16* Abf, const u16* Wt,
                                              const float* bq, const float* bk,
                                              const float* bv, u16* QKV) {
    int z = blockIdx.z;
    if (z == 2)
        gemm_body<1>(Abf + (size_t)2 * 4194304, Wt + (size_t)2 * 1048576, bv, 1.f,
                     QKV + (size_t)2 * 4194304);
    else if (z == 1)
        gemm_body<3>(Abf + (size_t)4194304, Wt + (size_t)1048576, bk, 1.f,
                     QKV + (size_t)4194304);
    else   // softmax scale AND log2(e) folded into Q so attn uses exp2 directly
        gemm_body<0>(Abf, Wt, bq, 0.125f * 1.44269504088896f, QKV);
}

// combine pre-normalized bf16 partials: Xc = x0*l0/(l0+l1) + x1*l1/(l0+l1)
// (verified in R5; l0 > 0 always since parity-0 owns k-tile 0 of every row)
__global__ __launch_bounds__(256) void k_combine(const u16* Xp, const float* Lp, u16* Xc) {
    size_t idx = (size_t)blockIdx.x * 256 + threadIdx.x;
    size_t e = idx * 8;
    int row = (int)(e >> 10), hh = ((int)e & 1023) >> 6;
    float l0 = Lp[(size_t)row * 16 + hh];
    float l1 = Lp[65536 + (size_t)row * 16 + hh];
    float s = 1.0f / (l0 + l1);
    float w0 = l0 * s, w1 = l1 * s;
    uint4v x0 = *(const uint4v*)(Xp + e);
    uint4v x1 = *(const uint4v*)(Xp + (size_t)4194304 + e);
    uint4v o;
    #pragma unroll
    for (int j = 0; j < 4; j++) {
        float a0 = bf2f(x0[j] & 0xffffu) * w0 + bf2f(x1[j] & 0xffffu) * w1;
        float a1 = bf2f(x0[j] >> 16)    * w0 + bf2f(x1[j] >> 16)    * w1;
        o[j] = cvtpk(a0, a1);
    }
    *(uint4v*)(Xc + e) = o;
}

__global__ __launch_bounds__(256) void k_gemm_out(const u16* Xc, const u16* Wt,
                                                  const float* bo, float* out) {
    gemm_body<2>(Xc, Wt, bo, 1.f, out);
}

// ---------------------------------------------------------------------------
// Causal flash attention v5: R8's LDS-shared staging + k-PARITY SPLIT across
// grid.z (kt = 2i+par). grid (16, 32, 2), 256 thr = 4 waves. Block (x,bh,par),
// j = 15-x: waves own q-tiles {4j..4j+3}; block computes k-tiles of its
// parity only (half the serial chain of R8; 1024 blocks = 4/CU = 16 waves/CU).
// Partials: pre-normalized bf16 O + f32 lsum (R5 scheme); k_combine merges.
// Staging/compute loop is R8's verbatim except the kt stride.
// ---------------------------------------------------------------------------
__global__ __launch_bounds__(256, 2) void k_attn(const u16* __restrict__ Qp,
                                                 const u16* __restrict__ Kp2,
                                                 const u16* __restrict__ Vp2,
                                                 u16* __restrict__ Xp, float* __restrict__ Lp) {
    const int bh = blockIdx.y, b = bh >> 4, h = bh & 15;
    const int t = threadIdx.x, lane = t & 63, w = t >> 6;
    const int lo = lane & 31, hi = lane >> 5;
    const int par = blockIdx.z;
    const int j = 15 - (int)blockIdx.x;        // heavy-first
    const int q0 = (j * 4 + w) * 32;           // this wave's q-tile
    const int NTw = j * 4 + w + 1;             // this wave's causal k-tiles (all parities)
    const int NPH = 2 * j + 2;                 // parity-tiles staged per block
    const u16* Qb = Qp + (size_t)(b * 2048) * 1024 + h * 64;
    const u16* Kb = Kp2 + (size_t)bh * 64 * 2048;
    const u16* Vb = Vp2 + (size_t)bh * 64 * 2048;

    __shared__ __align__(16) u16 Ks[2][2048];
    __shared__ __align__(16) u16 Vs[2][2048];

    short8 qf[4];
    #pragma unroll
    for (int c = 0; c < 4; c++)
        qf[c] = *(const short8*)(Qb + (size_t)(q0 + lo) * 1024 + c * 16 + hi * 8);

    f32x16 O0 = {}, O1 = {};
    float lsum = 0.f;
    const int qg = q0 + lo;

    // one packed tile = 2048 u16 = 4KB; 256 threads x 16B covers it in ONE round
#define STAGE(buf, kt) do {                                                              \
        gload16(Kb + (size_t)(kt) * 2048 + t * 8, Ks[buf] + t * 8);                      \
        gload16(Vb + (size_t)(kt) * 2048 + t * 8, Vs[buf] + t * 8);                      \
    } while (0)

    STAGE(0, par);
    for (int i = 0; i < NPH; i++) {
        __syncthreads();                       // publishes stage(i); fences buf reuse
        if (i + 1 < NPH) STAGE((i + 1) & 1, 2 * (i + 1) + par);
        const int kt = 2 * i + par;
        if (kt < NTw) {
            const u16* kl = Ks[i & 1];
            const u16* vl = Vs[i & 1];
            short8 kf[4], vf[4];
            #pragma unroll
            for (int c = 0; c < 4; c++) {
                kf[c] = *(const short8*)(kl + (c * 64 + lane) * 8);
                vf[c] = *(const short8*)(vl + (c * 64 + lane) * 8);
            }
            f32x16 S = {};
            #pragma unroll
            for (int c = 0; c < 4; c++)
                S = __builtin_amdgcn_mfma_f32_32x32x16_bf16(kf[c], qf[c], S, 0, 0, 0);
            const bool diag = (kt == NTw - 1);
            #pragma unroll
            for (int kc = 0; kc < 2; kc++) {
                float pv[8];
                #pragma unroll
                for (int jj = 0; jj < 8; jj++) {
                    int r = kc * 8 + jj;
                    float s = S[r];
                    if (diag) {
                        int kg = kt * 32 + (r & 3) + 8 * (r >> 2) + 4 * hi;
                        s = (kg <= qg) ? s : -1e30f;
                    }
                    pv[jj] = __builtin_amdgcn_exp2f(s);
                }
                lsum += (((pv[0] + pv[1]) + (pv[2] + pv[3])) +
                         ((pv[4] + pv[5]) + (pv[6] + pv[7])));
                u32 w0 = cvtpk(pv[0], pv[1]), w1 = cvtpk(pv[2], pv[3]);
                u32 w2 = cvtpk(pv[4], pv[5]), w3 = cvtpk(pv[6], pv[7]);
                auto r0 = __builtin_amdgcn_permlane32_swap(w0, w2, false, false);
                auto r1 = __builtin_amdgcn_permlane32_swap(w1, w3, false, false);
                uint4v fw; fw[0] = r0[0]; fw[1] = r1[0]; fw[2] = r0[1]; fw[3] = r1[1];
                short8 pf = __builtin_bit_cast(short8, fw);
                O0 = __builtin_amdgcn_mfma_f32_32x32x16_bf16(pf, vf[kc * 2 + 0], O0, 0, 0, 0);
                O1 = __builtin_amdgcn_mfma_f32_32x32x16_bf16(pf, vf[kc * 2 + 1], O1, 0, 0, 0);
            }
        }
    }
#undef STAGE

    // pre-normalized partial output (R5 scheme); guard empty parity ranges
    float ltot = lsum + __shfl_xor(lsum, 32, 64);
    u16* Xb = Xp + (size_t)par * 4194304;
    #pragma unroll
    for (int r = 0; r < 16; r++) {
        int qr = (r & 3) + 8 * (r >> 2) + 4 * hi;
        float lt = __shfl(ltot, qr, 64);       // normalizer of q-row qr
        float linv = lt > 0.f ? 1.f / lt : 0.f;
        size_t rowb = (size_t)(b * 2048 + q0 + qr) * 1024 + h * 64;
        Xb[rowb + lo]      = f2bf(O0[r] * linv);
        Xb[rowb + 32 + lo] = f2bf(O1[r] * linv);
    }
    if (hi == 0)
        Lp[(size_t)par * 65536 + (size_t)(b * 2048 + q0 + lo) * 16 + h] = ltot;
}

extern "C" void kernel_launch(void* const* d_in, const int* in_sizes, int n_in,
                              void* d_out, int out_size, void* d_ws, size_t ws_size,
                              hipStream_t stream) {
    (void)in_sizes; (void)n_in; (void)out_size; (void)ws_size;
    const float* q  = (const float*)d_in[0];
    const float* k  = (const float*)d_in[1];
    const float* v  = (const float*)d_in[2];
    const float* Wq = (const float*)d_in[3];
    const float* bq = (const float*)d_in[4];
    const float* Wk = (const float*)d_in[5];
    const float* bk = (const float*)d_in[6];
    const float* Wv = (const float*)d_in[7];
    const float* bv = (const float*)d_in[8];
    const float* Wo = (const float*)d_in[9];
    const float* bo = (const float*)d_in[10];

    // workspace layout (u16 units), R5-verified:
    //   [0, 4M)       Wt  : 4 x 1024x1024 bf16              (8 MB)
    //   [4M, 16M)     QKV : Q row-major, K packed, V packed (24 MB)
    //   [16M, 28M)    Abf : q,k,v bf16 (dead after k_proj)  (24 MB)
    //                 reused: Xp = Abf (2 segs), Xc = Abf + 2 segs
    //   [28M, +512KB) Lp  : 2 x 4096x16 f32
    u16*   Wt  = (u16*)d_ws;
    u16*   QKV = Wt + (size_t)4 * 1048576;
    u16*   Abf = QKV + (size_t)3 * 4194304;
    u16*   Xp  = Abf;                         // reuse (Abf dead after k_proj)
    u16*   Xc  = Abf + (size_t)2 * 4194304;
    float* Lp  = (float*)(Abf + (size_t)3 * 4194304);

    k_transw<<<dim3(32, 32, 4), dim3(32, 8), 0, stream>>>(Wq, Wk, Wv, Wo, Wt);
    k_cvt<<<dim3(2048, 1, 3), 256, 0, stream>>>(q, k, v, Abf);
    k_proj<<<dim3(8, 32, 3), 256, 0, stream>>>(Abf, Wt, bq, bk, bv, QKV);
    k_attn<<<dim3(16, 32, 2), 256, 0, stream>>>(QKV, QKV + (size_t)4194304,
                                                QKV + (size_t)2 * 4194304, Xp, Lp);
    k_combine<<<2048, 256, 0, stream>>>(Xp, Lp, Xc);
    k_gemm_out<<<dim3(8, 32), 256, 0, stream>>>(Xc, Wt + (size_t)3 * 1048576,
                                                bo, (float*)d_out);
}

// Round 11
// 135.459 us; speedup vs baseline: 1.0554x; 1.0075x over previous
//
#include <hip/hip_runtime.h>

typedef unsigned short u16;
typedef unsigned int   u32;
typedef __attribute__((ext_vector_type(8)))  short short8;
typedef __attribute__((ext_vector_type(4)))  float f32x4;
typedef __attribute__((ext_vector_type(16))) float f32x16;
typedef __attribute__((ext_vector_type(2)))  u32 uint2v;
typedef __attribute__((ext_vector_type(4)))  u32 uint4v;

#define DEV __device__ __forceinline__

DEV u16 f2bf(float f) {
    u32 u = __builtin_bit_cast(u32, f);
    return (u16)((u + 0x7fffu + ((u >> 16) & 1u)) >> 16);
}
DEV float bf2f(u32 u) { return __builtin_bit_cast(float, u << 16); }
DEV u32 cvtpk(float a, float b) {
    u32 r;
    asm("v_cvt_pk_bf16_f32 %0, %1, %2" : "=v"(r) : "v"(a), "v"(b));
    return r;
}
typedef const __attribute__((address_space(1))) u32 g_u32;
typedef __attribute__((address_space(3))) u32 l_u32;
DEV void gload16(const u16* g, u16* l) {
    __builtin_amdgcn_global_load_lds((g_u32*)g, (l_u32*)l, 16, 0, 0);
}

// ---------------------------------------------------------------------------
// Packed K layout (per bh, per 32-token tile, 4KB): elem index
//   ((c*2+hi)*32 + lo)*8 + e  holds  K[t=tblk*32+lo][d=c*16+hi*8+e]
// => fragment kf[c] = 16B at tile + (c*64+lane)*16B, fully linear.
// Packed V layout (per bh, per 32-token tile, 4KB): elem index
//   ((kc*2+c2)*64 + hi*32 + lo)*8 + e holds V[t=tblk*32+kc*16+hi*8+e][d=c2*32+lo]
// => fragment vf[kc*2+c2] = 16B at tile + ((kc*2+c2)*64+lane)*16B.
// ---------------------------------------------------------------------------

// GEMM: C[4096,1024] = A[4096,1024](bf16) @ Wt[n][k](bf16) + bias.
// 128x128 tile, BK=32, 256 thr (4 waves 2x2), 16x16x32 MFMA, m97 staging.
// OMODE 0: bf16 row-major (*oscale); 1: packed-V tiles; 2: f32 row-major;
//   3: packed-K tiles.
template<int OMODE>
DEV void gemm_body(const u16* __restrict__ A_, const u16* __restrict__ Bt,
                   const float* __restrict__ bias, float oscale, void* C_) {
    constexpr int Kd = 1024;
    const int m0 = blockIdx.y * 128, n0 = blockIdx.x * 128;
    const int t = threadIdx.x, lane = t & 63, w = t >> 6;
    const int wm = w >> 1, wn = w & 1;
    const int l15 = lane & 15, l4 = lane >> 4;
    __shared__ __align__(16) u16 As[128 * 32];
    __shared__ __align__(16) u16 Bs[128 * 32];
    f32x4 acc[4][4] = {};

    for (int k0 = 0; k0 < Kd; k0 += 32) {
        #pragma unroll
        for (int rnd = 0; rnd < 2; rnd++) {
            int cc = rnd * 256 + t, row = cc >> 2, slot = cc & 3;
            gload16(Bt + (size_t)(n0 + row) * Kd + k0 + slot * 8, Bs + cc * 8);
            gload16(A_ + (size_t)(m0 + row) * Kd + k0 + slot * 8, As + cc * 8);
        }
        __syncthreads();
        short8 af[4], bfr[4];
        #pragma unroll
        for (int i = 0; i < 4; i++) {
            af[i]  = *(const short8*)(As + (wm * 64 + i * 16 + l15) * 32 + l4 * 8);
            bfr[i] = *(const short8*)(Bs + (wn * 64 + i * 16 + l15) * 32 + l4 * 8);
        }
        #pragma unroll
        for (int i = 0; i < 4; i++)
            #pragma unroll
            for (int j = 0; j < 4; j++)
                acc[i][j] = __builtin_amdgcn_mfma_f32_16x16x32_bf16(af[i], bfr[j], acc[i][j], 0, 0, 0);
        __syncthreads();
    }

    #pragma unroll
    for (int i = 0; i < 4; i++) {
        #pragma unroll
        for (int j = 0; j < 4; j++) {
            int col = n0 + wn * 64 + j * 16 + l15;
            int mb  = m0 + wm * 64 + i * 16 + l4 * 4;
            float bv = bias[col];
            if (OMODE == 2) {
                float* C = (float*)C_;
                #pragma unroll
                for (int r = 0; r < 4; r++)
                    C[(size_t)(mb + r) * 1024 + col] = acc[i][j][r] + bv;
            } else if (OMODE == 0) {
                u16* C = (u16*)C_;
                #pragma unroll
                for (int r = 0; r < 4; r++)
                    C[(size_t)(mb + r) * 1024 + col] = f2bf((acc[i][j][r] + bv) * oscale);
            } else if (OMODE == 3) {
                // packed K tiles
                u16* C = (u16*)C_;
                int hh = col >> 6, dd = col & 63;
                int bb = mb >> 11, tt = mb & 2047;
                size_t tile = ((size_t)(bb * 16 + hh) * 64 + (tt >> 5)) * 2048;
                int c = dd >> 4, hi2 = (dd >> 3) & 1, e = dd & 7;
                int lob = tt & 31;
                #pragma unroll
                for (int r = 0; r < 4; r++)
                    C[tile + (size_t)((c * 2 + hi2) * 32 + lob + r) * 8 + e] =
                        f2bf(acc[i][j][r] + bv);
            } else {
                // packed V tiles: 4 consecutive tokens are contiguous elems
                u16* C = (u16*)C_;
                int hh = col >> 6, dd = col & 63;
                int bb = mb >> 11, tt = mb & 2047;
                size_t tile = ((size_t)(bb * 16 + hh) * 64 + (tt >> 5)) * 2048;
                int tin = tt & 31, kc = tin >> 4, hi2 = (tin >> 3) & 1, e0 = tin & 7;
                int c2 = dd >> 5, lo2 = dd & 31;
                size_t off = tile + (size_t)((kc * 2 + c2) * 64 + hi2 * 32 + lo2) * 8 + e0;
                uint2v pp;
                pp[0] = cvtpk(acc[i][j][0] + bv, acc[i][j][1] + bv);
                pp[1] = cvtpk(acc[i][j][2] + bv, acc[i][j][3] + bv);
                *(uint2v*)(C + off) = pp;
            }
        }
    }
}

// weights: W[k][n] f32 -> Wt[n][k] bf16
__global__ __launch_bounds__(256) void k_transw(const float* Wq, const float* Wk,
                                                const float* Wv, const float* Wo, u16* Wt) {
    int z = blockIdx.z;
    const float* W = z == 0 ? Wq : z == 1 ? Wk : z == 2 ? Wv : Wo;
    u16* O = Wt + (size_t)z * 1048576;
    __shared__ float tile[32][33];
    int n0 = blockIdx.x * 32, k0 = blockIdx.y * 32;
    int tx = threadIdx.x, ty = threadIdx.y;
    #pragma unroll
    for (int i = 0; i < 32; i += 8) tile[ty + i][tx] = W[(size_t)(k0 + ty + i) * 1024 + n0 + tx];
    __syncthreads();
    #pragma unroll
    for (int i = 0; i < 32; i += 8) O[(size_t)(n0 + ty + i) * 1024 + k0 + tx] = f2bf(tile[tx][ty + i]);
}

// q,k,v f32 -> bf16, fully coalesced, 8 elems/thread, exact coverage
__global__ __launch_bounds__(256) void k_cvt(const float* q, const float* k, const float* v,
                                             u16* Abf) {
    int z = blockIdx.z;
    const float* src = z == 0 ? q : z == 1 ? k : v;
    u16* dst = Abf + (size_t)z * 4194304;
    size_t i = ((size_t)blockIdx.x * 256 + threadIdx.x) * 8;
    float4 a = *(const float4*)(src + i);
    float4 b = *(const float4*)(src + i + 4);
    uint4v o;
    o[0] = cvtpk(a.x, a.y); o[1] = cvtpk(a.z, a.w);
    o[2] = cvtpk(b.x, b.y); o[3] = cvtpk(b.z, b.w);
    *(uint4v*)(dst + i) = o;
}

__global__ __launch_bounds__(256) void k_proj(const u16* Abf, const u16* Wt,
                                              const float* bq, const float* bk,
                                              const float* bv, u16* QKV) {
    int z = blockIdx.z;
    if (z == 2)
        gemm_body<1>(Abf + (size_t)2 * 4194304, Wt + (size_t)2 * 1048576, bv, 1.f,
                     QKV + (size_t)2 * 4194304);
    else if (z == 1)
        gemm_body<3>(Abf + (size_t)4194304, Wt + (size_t)1048576, bk, 1.f,
                     QKV + (size_t)4194304);
    else   // softmax scale AND log2(e) folded into Q so attn uses exp2 directly
        gemm_body<0>(Abf, Wt, bq, 0.125f * 1.44269504088896f, QKV);
}

// combine 3 pre-normalized bf16 partials: Xc = sum_i x_i * l_i / sum(l)
// (R5-verified scheme, extended to 3; l0 > 0 always since par 0 owns kt=0)
__global__ __launch_bounds__(256) void k_combine(const u16* Xp, const float* Lp, u16* Xc) {
    size_t idx = (size_t)blockIdx.x * 256 + threadIdx.x;
    size_t e = idx * 8;
    int row = (int)(e >> 10), hh = ((int)e & 1023) >> 6;
    float l0 = Lp[(size_t)row * 16 + hh];
    float l1 = Lp[65536 + (size_t)row * 16 + hh];
    float l2 = Lp[131072 + (size_t)row * 16 + hh];
    float s = 1.0f / (l0 + l1 + l2);
    float w0 = l0 * s, w1 = l1 * s, w2 = l2 * s;
    uint4v x0 = *(const uint4v*)(Xp + e);
    uint4v x1 = *(const uint4v*)(Xp + (size_t)4194304 + e);
    uint4v x2 = *(const uint4v*)(Xp + (size_t)2 * 4194304 + e);
    uint4v o;
    #pragma unroll
    for (int j = 0; j < 4; j++) {
        float a0 = bf2f(x0[j] & 0xffffu) * w0 + bf2f(x1[j] & 0xffffu) * w1
                 + bf2f(x2[j] & 0xffffu) * w2;
        float a1 = bf2f(x0[j] >> 16) * w0 + bf2f(x1[j] >> 16) * w1
                 + bf2f(x2[j] >> 16) * w2;
        o[j] = cvtpk(a0, a1);
    }
    *(uint4v*)(Xc + e) = o;
}

__global__ __launch_bounds__(256) void k_gemm_out(const u16* Xc, const u16* Wt,
                                                  const float* bo, float* out) {
    gemm_body<2>(Xc, Wt, bo, 1.f, out);
}

// ---------------------------------------------------------------------------
// Causal flash attention v6: R10's LDS-shared staging + BALANCED q-tile
// assignment + k-split x3.
// grid (16, 32, 3), 256 thr = 4 waves. Block (j=x, bh, par): wave w owns
// q-tile qt = w*16 + j (spread across the triangle -> near-uniform block
// work, phases 17..22 instead of 2..32). Block computes k-tiles kt = 3i+par.
// 1536 blocks = 6/CU = 24 waves/CU co-resident. Staging loop is R10's
// verbatim except the kt stride. Partials: pre-normalized bf16 O + f32 lsum.
// ---------------------------------------------------------------------------
__global__ __launch_bounds__(256, 2) void k_attn(const u16* __restrict__ Qp,
                                                 const u16* __restrict__ Kp2,
                                                 const u16* __restrict__ Vp2,
                                                 u16* __restrict__ Xp, float* __restrict__ Lp) {
    const int bh = blockIdx.y, b = bh >> 4, h = bh & 15;
    const int t = threadIdx.x, lane = t & 63, w = t >> 6;
    const int lo = lane & 31, hi = lane >> 5;
    const int par = blockIdx.z;                // 0..2
    const int j = (int)blockIdx.x;             // 0..15
    const int qt = w * 16 + j;                 // this wave's q-tile (0..63)
    const int q0 = qt * 32;
    const int NTw = qt + 1;                    // this wave's causal k-tiles
    const int NTmax = j + 49;                  // heaviest wave (w=3) range
    const int NPH = (NTmax - 1 - par) / 3 + 1; // parity-tiles staged per block
    const u16* Qb = Qp + (size_t)(b * 2048) * 1024 + h * 64;
    const u16* Kb = Kp2 + (size_t)bh * 64 * 2048;
    const u16* Vb = Vp2 + (size_t)bh * 64 * 2048;

    __shared__ __align__(16) u16 Ks[2][2048];
    __shared__ __align__(16) u16 Vs[2][2048];

    short8 qf[4];
    #pragma unroll
    for (int c = 0; c < 4; c++)
        qf[c] = *(const short8*)(Qb + (size_t)(q0 + lo) * 1024 + c * 16 + hi * 8);

    f32x16 O0 = {}, O1 = {};
    float lsum = 0.f;
    const int qg = q0 + lo;

    // one packed tile = 2048 u16 = 4KB; 256 threads x 16B covers it in ONE round
#define STAGE(buf, kt) do {                                                              \
        gload16(Kb + (size_t)(kt) * 2048 + t * 8, Ks[buf] + t * 8);                      \
        gload16(Vb + (size_t)(kt) * 2048 + t * 8, Vs[buf] + t * 8);                      \
    } while (0)

    STAGE(0, par);
    for (int i = 0; i < NPH; i++) {
        __syncthreads();                       // publishes stage(i); fences buf reuse
        if (i + 1 < NPH) STAGE((i + 1) & 1, 3 * (i + 1) + par);
        const int kt = 3 * i + par;
        if (kt < NTw) {
            const u16* kl = Ks[i & 1];
            const u16* vl = Vs[i & 1];
            short8 kf[4], vf[4];
            #pragma unroll
            for (int c = 0; c < 4; c++) {
                kf[c] = *(const short8*)(kl + (c * 64 + lane) * 8);
                vf[c] = *(const short8*)(vl + (c * 64 + lane) * 8);
            }
            f32x16 S = {};
            #pragma unroll
            for (int c = 0; c < 4; c++)
                S = __builtin_amdgcn_mfma_f32_32x32x16_bf16(kf[c], qf[c], S, 0, 0, 0);
            const bool diag = (kt == NTw - 1);
            #pragma unroll
            for (int kc = 0; kc < 2; kc++) {
                float pv[8];
                #pragma unroll
                for (int jj = 0; jj < 8; jj++) {
                    int r = kc * 8 + jj;
                    float s = S[r];
                    if (diag) {
                        int kg = kt * 32 + (r & 3) + 8 * (r >> 2) + 4 * hi;
                        s = (kg <= qg) ? s : -1e30f;
                    }
                    pv[jj] = __builtin_amdgcn_exp2f(s);
                }
                lsum += (((pv[0] + pv[1]) + (pv[2] + pv[3])) +
                         ((pv[4] + pv[5]) + (pv[6] + pv[7])));
                u32 w0 = cvtpk(pv[0], pv[1]), w1 = cvtpk(pv[2], pv[3]);
                u32 w2 = cvtpk(pv[4], pv[5]), w3 = cvtpk(pv[6], pv[7]);
                auto r0 = __builtin_amdgcn_permlane32_swap(w0, w2, false, false);
                auto r1 = __builtin_amdgcn_permlane32_swap(w1, w3, false, false);
                uint4v fw; fw[0] = r0[0]; fw[1] = r1[0]; fw[2] = r0[1]; fw[3] = r1[1];
                short8 pf = __builtin_bit_cast(short8, fw);
                O0 = __builtin_amdgcn_mfma_f32_32x32x16_bf16(pf, vf[kc * 2 + 0], O0, 0, 0, 0);
                O1 = __builtin_amdgcn_mfma_f32_32x32x16_bf16(pf, vf[kc * 2 + 1], O1, 0, 0, 0);
            }
        }
    }
#undef STAGE

    // pre-normalized partial output; empty parity ranges write zeros (lt=0)
    float ltot = lsum + __shfl_xor(lsum, 32, 64);
    u16* Xb = Xp + (size_t)par * 4194304;
    #pragma unroll
    for (int r = 0; r < 16; r++) {
        int qr = (r & 3) + 8 * (r >> 2) + 4 * hi;
        float lt = __shfl(ltot, qr, 64);       // normalizer of q-row qr
        float linv = lt > 0.f ? 1.f / lt : 0.f;
        size_t rowb = (size_t)(b * 2048 + q0 + qr) * 1024 + h * 64;
        Xb[rowb + lo]      = f2bf(O0[r] * linv);
        Xb[rowb + 32 + lo] = f2bf(O1[r] * linv);
    }
    if (hi == 0)
        Lp[(size_t)par * 65536 + (size_t)(b * 2048 + q0 + lo) * 16 + h] = ltot;
}

extern "C" void kernel_launch(void* const* d_in, const int* in_sizes, int n_in,
                              void* d_out, int out_size, void* d_ws, size_t ws_size,
                              hipStream_t stream) {
    (void)in_sizes; (void)n_in; (void)out_size; (void)ws_size;
    const float* q  = (const float*)d_in[0];
    const float* k  = (const float*)d_in[1];
    const float* v  = (const float*)d_in[2];
    const float* Wq = (const float*)d_in[3];
    const float* bq = (const float*)d_in[4];
    const float* Wk = (const float*)d_in[5];
    const float* bk = (const float*)d_in[6];
    const float* Wv = (const float*)d_in[7];
    const float* bv = (const float*)d_in[8];
    const float* Wo = (const float*)d_in[9];
    const float* bo = (const float*)d_in[10];

    // workspace layout (u16 units):
    //   [0, 4M)       Wt  : 4 x 1024x1024 bf16              (8 MB)
    //   [4M, 16M)     QKV : Q row-major, K packed, V packed (24 MB)
    //                 Q seg reused as Xc after k_attn (Q dead)
    //   [16M, 28M)    Abf : q,k,v bf16 (dead after k_proj)
    //                 reused: Xp = Abf (3 segs of 4M)
    //   [28M, +768KB) Lp  : 3 x 4096x16 f32
    u16*   Wt  = (u16*)d_ws;
    u16*   QKV = Wt + (size_t)4 * 1048576;
    u16*   Abf = QKV + (size_t)3 * 4194304;
    u16*   Xp  = Abf;                         // reuse (Abf dead after k_proj)
    u16*   Xc  = QKV;                         // reuse Q segment (dead after k_attn)
    float* Lp  = (float*)(Abf + (size_t)3 * 4194304);

    k_transw<<<dim3(32, 32, 4), dim3(32, 8), 0, stream>>>(Wq, Wk, Wv, Wo, Wt);
    k_cvt<<<dim3(2048, 1, 3), 256, 0, stream>>>(q, k, v, Abf);
    k_proj<<<dim3(8, 32, 3), 256, 0, stream>>>(Abf, Wt, bq, bk, bv, QKV);
    k_attn<<<dim3(16, 32, 3), 256, 0, stream>>>(QKV, QKV + (size_t)4194304,
                                                QKV + (size_t)2 * 4194304, Xp, Lp);
    k_combine<<<2048, 256, 0, stream>>>(Xp, Lp, Xc);
    k_gemm_out<<<dim3(8, 32), 256, 0, stream>>>(Xc, Wt + (size_t)3 * 1048576,
                                                bo, (float*)d_out);
}

// Round 12
// 131.163 us; speedup vs baseline: 1.0900x; 1.0328x over previous
//
#include <hip/hip_runtime.h>

typedef unsigned short u16;
typedef unsigned int   u32;
typedef __attribute__((ext_vector_type(8)))  short short8;
typedef __attribute__((ext_vector_type(4)))  float f32x4;
typedef __attribute__((ext_vector_type(16))) float f32x16;
typedef __attribute__((ext_vector_type(2)))  u32 uint2v;
typedef __attribute__((ext_vector_type(4)))  u32 uint4v;

#define DEV __device__ __forceinline__

DEV u16 f2bf(float f) {
    u32 u = __builtin_bit_cast(u32, f);
    return (u16)((u + 0x7fffu + ((u >> 16) & 1u)) >> 16);
}
DEV float bf2f(u32 u) { return __builtin_bit_cast(float, u << 16); }
DEV u32 cvtpk(float a, float b) {
    u32 r;
    asm("v_cvt_pk_bf16_f32 %0, %1, %2" : "=v"(r) : "v"(a), "v"(b));
    return r;
}
typedef const __attribute__((address_space(1))) u32 g_u32;
typedef __attribute__((address_space(3))) u32 l_u32;
DEV void gload16(const u16* g, u16* l) {
    __builtin_amdgcn_global_load_lds((g_u32*)g, (l_u32*)l, 16, 0, 0);
}

// ---------------------------------------------------------------------------
// Packed K layout (per bh, per 32-token tile, 4KB): elem index
//   ((c*2+hi)*32 + lo)*8 + e  holds  K[t=tblk*32+lo][d=c*16+hi*8+e]
// => fragment kf[c] = 16B at tile + (c*64+lane)*16B, fully linear.
// Packed V layout (per bh, per 32-token tile, 4KB): elem index
//   ((kc*2+c2)*64 + hi*32 + lo)*8 + e holds V[t=tblk*32+kc*16+hi*8+e][d=c2*32+lo]
// => fragment vf[kc*2+c2] = 16B at tile + ((kc*2+c2)*64+lane)*16B.
// ---------------------------------------------------------------------------

// GEMM: C[4096,1024] = A[4096,1024](bf16) @ Wt[n][k](bf16) + bias.
// 128x128 tile, BK=32, 256 thr (4 waves 2x2), 16x16x32 MFMA, m97 staging.
// OMODE 0: bf16 row-major (*oscale); 1: packed-V tiles; 2: f32 row-major;
//   3: packed-K tiles.
template<int OMODE>
DEV void gemm_body(const u16* __restrict__ A_, const u16* __restrict__ Bt,
                   const float* __restrict__ bias, float oscale, void* C_) {
    constexpr int Kd = 1024;
    const int m0 = blockIdx.y * 128, n0 = blockIdx.x * 128;
    const int t = threadIdx.x, lane = t & 63, w = t >> 6;
    const int wm = w >> 1, wn = w & 1;
    const int l15 = lane & 15, l4 = lane >> 4;
    __shared__ __align__(16) u16 As[128 * 32];
    __shared__ __align__(16) u16 Bs[128 * 32];
    f32x4 acc[4][4] = {};

    for (int k0 = 0; k0 < Kd; k0 += 32) {
        #pragma unroll
        for (int rnd = 0; rnd < 2; rnd++) {
            int cc = rnd * 256 + t, row = cc >> 2, slot = cc & 3;
            gload16(Bt + (size_t)(n0 + row) * Kd + k0 + slot * 8, Bs + cc * 8);
            gload16(A_ + (size_t)(m0 + row) * Kd + k0 + slot * 8, As + cc * 8);
        }
        __syncthreads();
        short8 af[4], bfr[4];
        #pragma unroll
        for (int i = 0; i < 4; i++) {
            af[i]  = *(const short8*)(As + (wm * 64 + i * 16 + l15) * 32 + l4 * 8);
            bfr[i] = *(const short8*)(Bs + (wn * 64 + i * 16 + l15) * 32 + l4 * 8);
        }
        #pragma unroll
        for (int i = 0; i < 4; i++)
            #pragma unroll
            for (int j = 0; j < 4; j++)
                acc[i][j] = __builtin_amdgcn_mfma_f32_16x16x32_bf16(af[i], bfr[j], acc[i][j], 0, 0, 0);
        __syncthreads();
    }

    #pragma unroll
    for (int i = 0; i < 4; i++) {
        #pragma unroll
        for (int j = 0; j < 4; j++) {
            int col = n0 + wn * 64 + j * 16 + l15;
            int mb  = m0 + wm * 64 + i * 16 + l4 * 4;
            float bv = bias[col];
            if (OMODE == 2) {
                float* C = (float*)C_;
                #pragma unroll
                for (int r = 0; r < 4; r++)
                    C[(size_t)(mb + r) * 1024 + col] = acc[i][j][r] + bv;
            } else if (OMODE == 0) {
                u16* C = (u16*)C_;
                #pragma unroll
                for (int r = 0; r < 4; r++)
                    C[(size_t)(mb + r) * 1024 + col] = f2bf((acc[i][j][r] + bv) * oscale);
            } else if (OMODE == 3) {
                // packed K tiles
                u16* C = (u16*)C_;
                int hh = col >> 6, dd = col & 63;
                int bb = mb >> 11, tt = mb & 2047;
                size_t tile = ((size_t)(bb * 16 + hh) * 64 + (tt >> 5)) * 2048;
                int c = dd >> 4, hi2 = (dd >> 3) & 1, e = dd & 7;
                int lob = tt & 31;
                #pragma unroll
                for (int r = 0; r < 4; r++)
                    C[tile + (size_t)((c * 2 + hi2) * 32 + lob + r) * 8 + e] =
                        f2bf(acc[i][j][r] + bv);
            } else {
                // packed V tiles: 4 consecutive tokens are contiguous elems
                u16* C = (u16*)C_;
                int hh = col >> 6, dd = col & 63;
                int bb = mb >> 11, tt = mb & 2047;
                size_t tile = ((size_t)(bb * 16 + hh) * 64 + (tt >> 5)) * 2048;
                int tin = tt & 31, kc = tin >> 4, hi2 = (tin >> 3) & 1, e0 = tin & 7;
                int c2 = dd >> 5, lo2 = dd & 31;
                size_t off = tile + (size_t)((kc * 2 + c2) * 64 + hi2 * 32 + lo2) * 8 + e0;
                uint2v pp;
                pp[0] = cvtpk(acc[i][j][0] + bv, acc[i][j][1] + bv);
                pp[1] = cvtpk(acc[i][j][2] + bv, acc[i][j][3] + bv);
                *(uint2v*)(C + off) = pp;
            }
        }
    }
}

// weights: W[k][n] f32 -> Wt[n][k] bf16
__global__ __launch_bounds__(256) void k_transw(const float* Wq, const float* Wk,
                                                const float* Wv, const float* Wo, u16* Wt) {
    int z = blockIdx.z;
    const float* W = z == 0 ? Wq : z == 1 ? Wk : z == 2 ? Wv : Wo;
    u16* O = Wt + (size_t)z * 1048576;
    __shared__ float tile[32][33];
    int n0 = blockIdx.x * 32, k0 = blockIdx.y * 32;
    int tx = threadIdx.x, ty = threadIdx.y;
    #pragma unroll
    for (int i = 0; i < 32; i += 8) tile[ty + i][tx] = W[(size_t)(k0 + ty + i) * 1024 + n0 + tx];
    __syncthreads();
    #pragma unroll
    for (int i = 0; i < 32; i += 8) O[(size_t)(n0 + ty + i) * 1024 + k0 + tx] = f2bf(tile[tx][ty + i]);
}

// q,k,v f32 -> bf16, fully coalesced, 8 elems/thread, exact coverage
__global__ __launch_bounds__(256) void k_cvt(const float* q, const float* k, const float* v,
                                             u16* Abf) {
    int z = blockIdx.z;
    const float* src = z == 0 ? q : z == 1 ? k : v;
    u16* dst = Abf + (size_t)z * 4194304;
    size_t i = ((size_t)blockIdx.x * 256 + threadIdx.x) * 8;
    float4 a = *(const float4*)(src + i);
    float4 b = *(const float4*)(src + i + 4);
    uint4v o;
    o[0] = cvtpk(a.x, a.y); o[1] = cvtpk(a.z, a.w);
    o[2] = cvtpk(b.x, b.y); o[3] = cvtpk(b.z, b.w);
    *(uint4v*)(dst + i) = o;
}

__global__ __launch_bounds__(256) void k_proj(const u16* Abf, const u16* Wt,
                                              const float* bq, const float* bk,
                                              const float* bv, u16* QKV) {
    int z = blockIdx.z;
    if (z == 2)
        gemm_body<1>(Abf + (size_t)2 * 4194304, Wt + (size_t)2 * 1048576, bv, 1.f,
                     QKV + (size_t)2 * 4194304);
    else if (z == 1)
        gemm_body<3>(Abf + (size_t)4194304, Wt + (size_t)1048576, bk, 1.f,
                     QKV + (size_t)4194304);
    else   // softmax scale AND log2(e) folded into Q so attn uses exp2 directly
        gemm_body<0>(Abf, Wt, bq, 0.125f * 1.44269504088896f, QKV);
}

// combine 3 pre-normalized bf16 partials: Xc = sum_i x_i * l_i / sum(l)
// (R5-verified scheme, extended to 3; l0 > 0 always since par 0 owns kt=0)
__global__ __launch_bounds__(256) void k_combine(const u16* Xp, const float* Lp, u16* Xc) {
    size_t idx = (size_t)blockIdx.x * 256 + threadIdx.x;
    size_t e = idx * 8;
    int row = (int)(e >> 10), hh = ((int)e & 1023) >> 6;
    float l0 = Lp[(size_t)row * 16 + hh];
    float l1 = Lp[65536 + (size_t)row * 16 + hh];
    float l2 = Lp[131072 + (size_t)row * 16 + hh];
    float s = 1.0f / (l0 + l1 + l2);
    float w0 = l0 * s, w1 = l1 * s, w2 = l2 * s;
    uint4v x0 = *(const uint4v*)(Xp + e);
    uint4v x1 = *(const uint4v*)(Xp + (size_t)4194304 + e);
    uint4v x2 = *(const uint4v*)(Xp + (size_t)2 * 4194304 + e);
    uint4v o;
    #pragma unroll
    for (int j = 0; j < 4; j++) {
        float a0 = bf2f(x0[j] & 0xffffu) * w0 + bf2f(x1[j] & 0xffffu) * w1
                 + bf2f(x2[j] & 0xffffu) * w2;
        float a1 = bf2f(x0[j] >> 16) * w0 + bf2f(x1[j] >> 16) * w1
                 + bf2f(x2[j] >> 16) * w2;
        o[j] = cvtpk(a0, a1);
    }
    *(uint4v*)(Xc + e) = o;
}

__global__ __launch_bounds__(256) void k_gemm_out(const u16* Xc, const u16* Wt,
                                                  const float* bo, float* out) {
    gemm_body<2>(Xc, Wt, bo, 1.f, out);
}

// ---------------------------------------------------------------------------
// Causal flash attention v7: BARRIER-FREE, registers only.
// grid (16, 32, 3), 256 thr = 4 waves, NO LDS, NO __syncthreads.
// Block (j=x, bh, par): wave w owns q-tile qt = w*16 + j (balanced, R11);
// wave independently walks kt = par, par+3, ... < qt+1, loading its own K/V
// fragments from packed tiles (fully-coalesced 1KB VMEM reads, R5-verified
// LOADKV) into double-buffered registers. Latency hidden by 1-tile register
// prefetch x ~24 independent waves/CU. Partials: pre-normalized bf16 O +
// f32 lsum (R11-verified epilogue); k_combine merges.
// ---------------------------------------------------------------------------
__global__ __launch_bounds__(256, 3) void k_attn(const u16* __restrict__ Qp,
                                                 const u16* __restrict__ Kp2,
                                                 const u16* __restrict__ Vp2,
                                                 u16* __restrict__ Xp, float* __restrict__ Lp) {
    const int bh = blockIdx.y, b = bh >> 4, h = bh & 15;
    const int t = threadIdx.x, lane = t & 63, w = t >> 6;
    const int lo = lane & 31, hi = lane >> 5;
    const int par = blockIdx.z;                // 0..2
    const int j = (int)blockIdx.x;             // 0..15
    const int qt = w * 16 + j;                 // this wave's q-tile (0..63)
    const int q0 = qt * 32;
    const int NTw = qt + 1;                    // this wave's causal k-tiles
    const u16* Qb = Qp + (size_t)(b * 2048) * 1024 + h * 64;
    const u16* Kb = Kp2 + (size_t)bh * 64 * 2048;
    const u16* Vb = Vp2 + (size_t)bh * 64 * 2048;

    short8 qf[4];
    #pragma unroll
    for (int c = 0; c < 4; c++)
        qf[c] = *(const short8*)(Qb + (size_t)(q0 + lo) * 1024 + c * 16 + hi * 8);

    f32x16 O0 = {}, O1 = {};
    float lsum = 0.f;
    const int qg = q0 + lo;

#define LOADKV(KF, VF, kt) do {                                                          \
        const u16* kt_ = Kb + (size_t)(kt) * 2048;                                       \
        const u16* vt_ = Vb + (size_t)(kt) * 2048;                                       \
        _Pragma("unroll")                                                                \
        for (int c = 0; c < 4; c++)                                                      \
            KF[c] = *(const short8*)(kt_ + c * 512 + lane * 8);                          \
        _Pragma("unroll")                                                                \
        for (int jj = 0; jj < 4; jj++)                                                   \
            VF[jj] = *(const short8*)(vt_ + jj * 512 + lane * 8);                        \
    } while (0)

#define COMPUTE(KF, VF, kt) do {                                                          \
        f32x16 S = {};                                                                    \
        _Pragma("unroll")                                                                 \
        for (int c = 0; c < 4; c++)                                                       \
            S = __builtin_amdgcn_mfma_f32_32x32x16_bf16(KF[c], qf[c], S, 0, 0, 0);        \
        const bool diag = ((kt) == NTw - 1);                                              \
        _Pragma("unroll")                                                                 \
        for (int kc = 0; kc < 2; kc++) {                                                  \
            float pv[8];                                                                  \
            _Pragma("unroll")                                                             \
            for (int jj = 0; jj < 8; jj++) {                                              \
                int r = kc * 8 + jj;                                                      \
                float s = S[r];                                                           \
                if (diag) {                                                               \
                    int kg = (kt) * 32 + (r & 3) + 8 * (r >> 2) + 4 * hi;                 \
                    s = (kg <= qg) ? s : -1e30f;                                          \
                }                                                                         \
                pv[jj] = __builtin_amdgcn_exp2f(s);                                       \
            }                                                                             \
            lsum += (((pv[0] + pv[1]) + (pv[2] + pv[3])) +                                \
                     ((pv[4] + pv[5]) + (pv[6] + pv[7])));                                \
            u32 w0 = cvtpk(pv[0], pv[1]), w1 = cvtpk(pv[2], pv[3]);                       \
            u32 w2 = cvtpk(pv[4], pv[5]), w3 = cvtpk(pv[6], pv[7]);                       \
            auto r0 = __builtin_amdgcn_permlane32_swap(w0, w2, false, false);             \
            auto r1 = __builtin_amdgcn_permlane32_swap(w1, w3, false, false);             \
            uint4v fw; fw[0] = r0[0]; fw[1] = r1[0]; fw[2] = r0[1]; fw[3] = r1[1];        \
            short8 pf = __builtin_bit_cast(short8, fw);                                   \
            O0 = __builtin_amdgcn_mfma_f32_32x32x16_bf16(pf, VF[kc * 2 + 0], O0, 0, 0, 0);\
            O1 = __builtin_amdgcn_mfma_f32_32x32x16_bf16(pf, VF[kc * 2 + 1], O1, 0, 0, 0);\
        }                                                                                 \
    } while (0)

    {
        short8 kf0[4], vf0[4], kf1[4], vf1[4];
        int kt = par;
        if (kt < NTw) {
            LOADKV(kf0, vf0, kt);
            while (true) {
                if (kt + 3 < NTw) LOADKV(kf1, vf1, kt + 3);
                COMPUTE(kf0, vf0, kt);
                kt += 3;
                if (kt >= NTw) break;
                if (kt + 3 < NTw) LOADKV(kf0, vf0, kt + 3);
                COMPUTE(kf1, vf1, kt);
                kt += 3;
                if (kt >= NTw) break;
            }
        }
    }
#undef LOADKV
#undef COMPUTE

    // pre-normalized partial output; empty parity ranges write zeros (lt=0)
    float ltot = lsum + __shfl_xor(lsum, 32, 64);
    u16* Xb = Xp + (size_t)par * 4194304;
    #pragma unroll
    for (int r = 0; r < 16; r++) {
        int qr = (r & 3) + 8 * (r >> 2) + 4 * hi;
        float lt = __shfl(ltot, qr, 64);       // normalizer of q-row qr
        float linv = lt > 0.f ? 1.f / lt : 0.f;
        size_t rowb = (size_t)(b * 2048 + q0 + qr) * 1024 + h * 64;
        Xb[rowb + lo]      = f2bf(O0[r] * linv);
        Xb[rowb + 32 + lo] = f2bf(O1[r] * linv);
    }
    if (hi == 0)
        Lp[(size_t)par * 65536 + (size_t)(b * 2048 + q0 + lo) * 16 + h] = ltot;
}

extern "C" void kernel_launch(void* const* d_in, const int* in_sizes, int n_in,
                              void* d_out, int out_size, void* d_ws, size_t ws_size,
                              hipStream_t stream) {
    (void)in_sizes; (void)n_in; (void)out_size; (void)ws_size;
    const float* q  = (const float*)d_in[0];
    const float* k  = (const float*)d_in[1];
    const float* v  = (const float*)d_in[2];
    const float* Wq = (const float*)d_in[3];
    const float* bq = (const float*)d_in[4];
    const float* Wk = (const float*)d_in[5];
    const float* bk = (const float*)d_in[6];
    const float* Wv = (const float*)d_in[7];
    const float* bv = (const float*)d_in[8];
    const float* Wo = (const float*)d_in[9];
    const float* bo = (const float*)d_in[10];

    // workspace layout (u16 units):
    //   [0, 4M)       Wt  : 4 x 1024x1024 bf16              (8 MB)
    //   [4M, 16M)     QKV : Q row-major, K packed, V packed (24 MB)
    //                 Q seg reused as Xc after k_attn (Q dead)
    //   [16M, 28M)    Abf : q,k,v bf16 (dead after k_proj)
    //                 reused: Xp = Abf (3 segs of 4M)
    //   [28M, +768KB) Lp  : 3 x 4096x16 f32
    u16*   Wt  = (u16*)d_ws;
    u16*   QKV = Wt + (size_t)4 * 1048576;
    u16*   Abf = QKV + (size_t)3 * 4194304;
    u16*   Xp  = Abf;                         // reuse (Abf dead after k_proj)
    u16*   Xc  = QKV;                         // reuse Q segment (dead after k_attn)
    float* Lp  = (float*)(Abf + (size_t)3 * 4194304);

    k_transw<<<dim3(32, 32, 4), dim3(32, 8), 0, stream>>>(Wq, Wk, Wv, Wo, Wt);
    k_cvt<<<dim3(2048, 1, 3), 256, 0, stream>>>(q, k, v, Abf);
    k_proj<<<dim3(8, 32, 3), 256, 0, stream>>>(Abf, Wt, bq, bk, bv, QKV);
    k_attn<<<dim3(16, 32, 3), 256, 0, stream>>>(QKV, QKV + (size_t)4194304,
                                                QKV + (size_t)2 * 4194304, Xp, Lp);
    k_combine<<<2048, 256, 0, stream>>>(Xp, Lp, Xc);
    k_gemm_out<<<dim3(8, 32), 256, 0, stream>>>(Xc, Wt + (size_t)3 * 1048576,
                                                bo, (float*)d_out);
}

// Round 13
// 126.694 us; speedup vs baseline: 1.1285x; 1.0353x over previous
//
#include <hip/hip_runtime.h>

typedef unsigned short u16;
typedef unsigned int   u32;
typedef __attribute__((ext_vector_type(8)))  short short8;
typedef __attribute__((ext_vector_type(4)))  float f32x4;
typedef __attribute__((ext_vector_type(16))) float f32x16;
typedef __attribute__((ext_vector_type(2)))  u32 uint2v;
typedef __attribute__((ext_vector_type(4)))  u32 uint4v;

#define DEV __device__ __forceinline__

DEV u16 f2bf(float f) {
    u32 u = __builtin_bit_cast(u32, f);
    return (u16)((u + 0x7fffu + ((u >> 16) & 1u)) >> 16);
}
DEV float bf2f(u32 u) { return __builtin_bit_cast(float, u << 16); }
DEV u32 cvtpk(float a, float b) {
    u32 r;
    asm("v_cvt_pk_bf16_f32 %0, %1, %2" : "=v"(r) : "v"(a), "v"(b));
    return r;
}
typedef const __attribute__((address_space(1))) u32 g_u32;
typedef __attribute__((address_space(3))) u32 l_u32;
DEV void gload16(const u16* g, u16* l) {
    __builtin_amdgcn_global_load_lds((g_u32*)g, (l_u32*)l, 16, 0, 0);
}

// ---------------------------------------------------------------------------
// Packed K layout (per bh, per 32-token tile, 4KB): elem index
//   ((c*2+hi)*32 + lo)*8 + e  holds  K[t=tblk*32+lo][d=c*16+hi*8+e]
// => fragment kf[c] = 16B at tile + (c*64+lane)*16B, fully linear.
// Packed V layout (per bh, per 32-token tile, 4KB): elem index
//   ((kc*2+c2)*64 + hi*32 + lo)*8 + e holds V[t=tblk*32+kc*16+hi*8+e][d=c2*32+lo]
// => fragment vf[kc*2+c2] = 16B at tile + ((kc*2+c2)*64+lane)*16B.
// ---------------------------------------------------------------------------

// GEMM: C[4096,1024] = A[4096,1024](bf16) @ Wt[n][k](bf16) + bias.
// 128x128 tile, BK=32, 256 thr (4 waves 2x2), 16x16x32 MFMA, m97 staging.
// OMODE 0: bf16 row-major (*oscale); 1: packed-V tiles; 2: f32 row-major;
//   3: packed-K tiles.
template<int OMODE>
DEV void gemm_body(const u16* __restrict__ A_, const u16* __restrict__ Bt,
                   const float* __restrict__ bias, float oscale, void* C_) {
    constexpr int Kd = 1024;
    const int m0 = blockIdx.y * 128, n0 = blockIdx.x * 128;
    const int t = threadIdx.x, lane = t & 63, w = t >> 6;
    const int wm = w >> 1, wn = w & 1;
    const int l15 = lane & 15, l4 = lane >> 4;
    __shared__ __align__(16) u16 As[128 * 32];
    __shared__ __align__(16) u16 Bs[128 * 32];
    f32x4 acc[4][4] = {};

    for (int k0 = 0; k0 < Kd; k0 += 32) {
        #pragma unroll
        for (int rnd = 0; rnd < 2; rnd++) {
            int cc = rnd * 256 + t, row = cc >> 2, slot = cc & 3;
            gload16(Bt + (size_t)(n0 + row) * Kd + k0 + slot * 8, Bs + cc * 8);
            gload16(A_ + (size_t)(m0 + row) * Kd + k0 + slot * 8, As + cc * 8);
        }
        __syncthreads();
        short8 af[4], bfr[4];
        #pragma unroll
        for (int i = 0; i < 4; i++) {
            af[i]  = *(const short8*)(As + (wm * 64 + i * 16 + l15) * 32 + l4 * 8);
            bfr[i] = *(const short8*)(Bs + (wn * 64 + i * 16 + l15) * 32 + l4 * 8);
        }
        #pragma unroll
        for (int i = 0; i < 4; i++)
            #pragma unroll
            for (int j = 0; j < 4; j++)
                acc[i][j] = __builtin_amdgcn_mfma_f32_16x16x32_bf16(af[i], bfr[j], acc[i][j], 0, 0, 0);
        __syncthreads();
    }

    #pragma unroll
    for (int i = 0; i < 4; i++) {
        #pragma unroll
        for (int j = 0; j < 4; j++) {
            int col = n0 + wn * 64 + j * 16 + l15;
            int mb  = m0 + wm * 64 + i * 16 + l4 * 4;
            float bv = bias[col];
            if (OMODE == 2) {
                float* C = (float*)C_;
                #pragma unroll
                for (int r = 0; r < 4; r++)
                    C[(size_t)(mb + r) * 1024 + col] = acc[i][j][r] + bv;
            } else if (OMODE == 0) {
                u16* C = (u16*)C_;
                #pragma unroll
                for (int r = 0; r < 4; r++)
                    C[(size_t)(mb + r) * 1024 + col] = f2bf((acc[i][j][r] + bv) * oscale);
            } else if (OMODE == 3) {
                // packed K tiles
                u16* C = (u16*)C_;
                int hh = col >> 6, dd = col & 63;
                int bb = mb >> 11, tt = mb & 2047;
                size_t tile = ((size_t)(bb * 16 + hh) * 64 + (tt >> 5)) * 2048;
                int c = dd >> 4, hi2 = (dd >> 3) & 1, e = dd & 7;
                int lob = tt & 31;
                #pragma unroll
                for (int r = 0; r < 4; r++)
                    C[tile + (size_t)((c * 2 + hi2) * 32 + lob + r) * 8 + e] =
                        f2bf(acc[i][j][r] + bv);
            } else {
                // packed V tiles: 4 consecutive tokens are contiguous elems
                u16* C = (u16*)C_;
                int hh = col >> 6, dd = col & 63;
                int bb = mb >> 11, tt = mb & 2047;
                size_t tile = ((size_t)(bb * 16 + hh) * 64 + (tt >> 5)) * 2048;
                int tin = tt & 31, kc = tin >> 4, hi2 = (tin >> 3) & 1, e0 = tin & 7;
                int c2 = dd >> 5, lo2 = dd & 31;
                size_t off = tile + (size_t)((kc * 2 + c2) * 64 + hi2 * 32 + lo2) * 8 + e0;
                uint2v pp;
                pp[0] = cvtpk(acc[i][j][0] + bv, acc[i][j][1] + bv);
                pp[1] = cvtpk(acc[i][j][2] + bv, acc[i][j][3] + bv);
                *(uint2v*)(C + off) = pp;
            }
        }
    }
}

// weights: W[k][n] f32 -> Wt[n][k] bf16
__global__ __launch_bounds__(256) void k_transw(const float* Wq, const float* Wk,
                                                const float* Wv, const float* Wo, u16* Wt) {
    int z = blockIdx.z;
    const float* W = z == 0 ? Wq : z == 1 ? Wk : z == 2 ? Wv : Wo;
    u16* O = Wt + (size_t)z * 1048576;
    __shared__ float tile[32][33];
    int n0 = blockIdx.x * 32, k0 = blockIdx.y * 32;
    int tx = threadIdx.x, ty = threadIdx.y;
    #pragma unroll
    for (int i = 0; i < 32; i += 8) tile[ty + i][tx] = W[(size_t)(k0 + ty + i) * 1024 + n0 + tx];
    __syncthreads();
    #pragma unroll
    for (int i = 0; i < 32; i += 8) O[(size_t)(n0 + ty + i) * 1024 + k0 + tx] = f2bf(tile[tx][ty + i]);
}

// q,k,v f32 -> bf16, fully coalesced, 8 elems/thread, exact coverage
__global__ __launch_bounds__(256) void k_cvt(const float* q, const float* k, const float* v,
                                             u16* Abf) {
    int z = blockIdx.z;
    const float* src = z == 0 ? q : z == 1 ? k : v;
    u16* dst = Abf + (size_t)z * 4194304;
    size_t i = ((size_t)blockIdx.x * 256 + threadIdx.x) * 8;
    float4 a = *(const float4*)(src + i);
    float4 b = *(const float4*)(src + i + 4);
    uint4v o;
    o[0] = cvtpk(a.x, a.y); o[1] = cvtpk(a.z, a.w);
    o[2] = cvtpk(b.x, b.y); o[3] = cvtpk(b.z, b.w);
    *(uint4v*)(dst + i) = o;
}

__global__ __launch_bounds__(256) void k_proj(const u16* Abf, const u16* Wt,
                                              const float* bq, const float* bk,
                                              const float* bv, u16* QKV) {
    int z = blockIdx.z;
    if (z == 2)
        gemm_body<1>(Abf + (size_t)2 * 4194304, Wt + (size_t)2 * 1048576, bv, 1.f,
                     QKV + (size_t)2 * 4194304);
    else if (z == 1)
        gemm_body<3>(Abf + (size_t)4194304, Wt + (size_t)1048576, bk, 1.f,
                     QKV + (size_t)4194304);
    else   // softmax scale AND log2(e) folded into Q so attn uses exp2 directly
        gemm_body<0>(Abf, Wt, bq, 0.125f * 1.44269504088896f, QKV);
}

// combine 3 pre-normalized bf16 partials: Xc = sum_i x_i * l_i / sum(l)
// (R5-verified scheme, extended to 3; l0 > 0 always since par 0 owns kt=0)
__global__ __launch_bounds__(256) void k_combine(const u16* Xp, const float* Lp, u16* Xc) {
    size_t idx = (size_t)blockIdx.x * 256 + threadIdx.x;
    size_t e = idx * 8;
    int row = (int)(e >> 10), hh = ((int)e & 1023) >> 6;
    float l0 = Lp[(size_t)row * 16 + hh];
    float l1 = Lp[65536 + (size_t)row * 16 + hh];
    float l2 = Lp[131072 + (size_t)row * 16 + hh];
    float s = 1.0f / (l0 + l1 + l2);
    float w0 = l0 * s, w1 = l1 * s, w2 = l2 * s;
    uint4v x0 = *(const uint4v*)(Xp + e);
    uint4v x1 = *(const uint4v*)(Xp + (size_t)4194304 + e);
    uint4v x2 = *(const uint4v*)(Xp + (size_t)2 * 4194304 + e);
    uint4v o;
    #pragma unroll
    for (int j = 0; j < 4; j++) {
        float a0 = bf2f(x0[j] & 0xffffu) * w0 + bf2f(x1[j] & 0xffffu) * w1
                 + bf2f(x2[j] & 0xffffu) * w2;
        float a1 = bf2f(x0[j] >> 16) * w0 + bf2f(x1[j] >> 16) * w1
                 + bf2f(x2[j] >> 16) * w2;
        o[j] = cvtpk(a0, a1);
    }
    *(uint4v*)(Xc + e) = o;
}

__global__ __launch_bounds__(256) void k_gemm_out(const u16* Xc, const u16* Wt,
                                                  const float* bo, float* out) {
    gemm_body<2>(Xc, Wt, bo, 1.f, out);
}

// ---------------------------------------------------------------------------
// Causal flash attention v8: R12's barrier-free register kernel + XCD-LOCAL
// bh mapping. 1-D grid of 1536; bh = id & 31 so all 48 blocks of one bh are
// spaced 32 apart in dispatch order == same XCD under round-robin (32 = 0
// mod 8). 4 bh per XCD x 512KB K/V = 2MB, fits the 4MB per-XCD L2 ->
// per-tile loads become L2 hits, hidden by the 1-tile register prefetch.
// Decode: j = (id>>5)&15, par = id>>9. Compute identical to R12.
// ---------------------------------------------------------------------------
__global__ __launch_bounds__(256, 3) void k_attn(const u16* __restrict__ Qp,
                                                 const u16* __restrict__ Kp2,
                                                 const u16* __restrict__ Vp2,
                                                 u16* __restrict__ Xp, float* __restrict__ Lp) {
    const int id = (int)blockIdx.x;
    const int bh = id & 31;                    // same-XCD family (id mod 8 fixed)
    const int j = (id >> 5) & 15;              // 0..15
    const int par = id >> 9;                   // 0..2
    const int b = bh >> 4, h = bh & 15;
    const int t = threadIdx.x, lane = t & 63, w = t >> 6;
    const int lo = lane & 31, hi = lane >> 5;
    const int qt = w * 16 + j;                 // this wave's q-tile (0..63)
    const int q0 = qt * 32;
    const int NTw = qt + 1;                    // this wave's causal k-tiles
    const u16* Qb = Qp + (size_t)(b * 2048) * 1024 + h * 64;
    const u16* Kb = Kp2 + (size_t)bh * 64 * 2048;
    const u16* Vb = Vp2 + (size_t)bh * 64 * 2048;

    short8 qf[4];
    #pragma unroll
    for (int c = 0; c < 4; c++)
        qf[c] = *(const short8*)(Qb + (size_t)(q0 + lo) * 1024 + c * 16 + hi * 8);

    f32x16 O0 = {}, O1 = {};
    float lsum = 0.f;
    const int qg = q0 + lo;

#define LOADKV(KF, VF, kt) do {                                                          \
        const u16* kt_ = Kb + (size_t)(kt) * 2048;                                       \
        const u16* vt_ = Vb + (size_t)(kt) * 2048;                                       \
        _Pragma("unroll")                                                                \
        for (int c = 0; c < 4; c++)                                                      \
            KF[c] = *(const short8*)(kt_ + c * 512 + lane * 8);                          \
        _Pragma("unroll")                                                                \
        for (int jj = 0; jj < 4; jj++)                                                   \
            VF[jj] = *(const short8*)(vt_ + jj * 512 + lane * 8);                        \
    } while (0)

#define COMPUTE(KF, VF, kt) do {                                                          \
        f32x16 S = {};                                                                    \
        _Pragma("unroll")                                                                 \
        for (int c = 0; c < 4; c++)                                                       \
            S = __builtin_amdgcn_mfma_f32_32x32x16_bf16(KF[c], qf[c], S, 0, 0, 0);        \
        const bool diag = ((kt) == NTw - 1);                                              \
        _Pragma("unroll")                                                                 \
        for (int kc = 0; kc < 2; kc++) {                                                  \
            float pv[8];                                                                  \
            _Pragma("unroll")                                                             \
            for (int jj = 0; jj < 8; jj++) {                                              \
                int r = kc * 8 + jj;                                                      \
                float s = S[r];                                                           \
                if (diag) {                                                               \
                    int kg = (kt) * 32 + (r & 3) + 8 * (r >> 2) + 4 * hi;                 \
                    s = (kg <= qg) ? s : -1e30f;                                          \
                }                                                                         \
                pv[jj] = __builtin_amdgcn_exp2f(s);                                       \
            }                                                                             \
            lsum += (((pv[0] + pv[1]) + (pv[2] + pv[3])) +                                \
                     ((pv[4] + pv[5]) + (pv[6] + pv[7])));                                \
            u32 w0 = cvtpk(pv[0], pv[1]), w1 = cvtpk(pv[2], pv[3]);                       \
            u32 w2 = cvtpk(pv[4], pv[5]), w3 = cvtpk(pv[6], pv[7]);                       \
            auto r0 = __builtin_amdgcn_permlane32_swap(w0, w2, false, false);             \
            auto r1 = __builtin_amdgcn_permlane32_swap(w1, w3, false, false);             \
            uint4v fw; fw[0] = r0[0]; fw[1] = r1[0]; fw[2] = r0[1]; fw[3] = r1[1];        \
            short8 pf = __builtin_bit_cast(short8, fw);                                   \
            O0 = __builtin_amdgcn_mfma_f32_32x32x16_bf16(pf, VF[kc * 2 + 0], O0, 0, 0, 0);\
            O1 = __builtin_amdgcn_mfma_f32_32x32x16_bf16(pf, VF[kc * 2 + 1], O1, 0, 0, 0);\
        }                                                                                 \
    } while (0)

    {
        short8 kf0[4], vf0[4], kf1[4], vf1[4];
        int kt = par;
        if (kt < NTw) {
            LOADKV(kf0, vf0, kt);
            while (true) {
                if (kt + 3 < NTw) LOADKV(kf1, vf1, kt + 3);
                COMPUTE(kf0, vf0, kt);
                kt += 3;
                if (kt >= NTw) break;
                if (kt + 3 < NTw) LOADKV(kf0, vf0, kt + 3);
                COMPUTE(kf1, vf1, kt);
                kt += 3;
                if (kt >= NTw) break;
            }
        }
    }
#undef LOADKV
#undef COMPUTE

    // pre-normalized partial output; empty parity ranges write zeros (lt=0)
    float ltot = lsum + __shfl_xor(lsum, 32, 64);
    u16* Xb = Xp + (size_t)par * 4194304;
    #pragma unroll
    for (int r = 0; r < 16; r++) {
        int qr = (r & 3) + 8 * (r >> 2) + 4 * hi;
        float lt = __shfl(ltot, qr, 64);       // normalizer of q-row qr
        float linv = lt > 0.f ? 1.f / lt : 0.f;
        size_t rowb = (size_t)(b * 2048 + q0 + qr) * 1024 + h * 64;
        Xb[rowb + lo]      = f2bf(O0[r] * linv);
        Xb[rowb + 32 + lo] = f2bf(O1[r] * linv);
    }
    if (hi == 0)
        Lp[(size_t)par * 65536 + (size_t)(b * 2048 + q0 + lo) * 16 + h] = ltot;
}

extern "C" void kernel_launch(void* const* d_in, const int* in_sizes, int n_in,
                              void* d_out, int out_size, void* d_ws, size_t ws_size,
                              hipStream_t stream) {
    (void)in_sizes; (void)n_in; (void)out_size; (void)ws_size;
    const float* q  = (const float*)d_in[0];
    const float* k  = (const float*)d_in[1];
    const float* v  = (const float*)d_in[2];
    const float* Wq = (const float*)d_in[3];
    const float* bq = (const float*)d_in[4];
    const float* Wk = (const float*)d_in[5];
    const float* bk = (const float*)d_in[6];
    const float* Wv = (const float*)d_in[7];
    const float* bv = (const float*)d_in[8];
    const float* Wo = (const float*)d_in[9];
    const float* bo = (const float*)d_in[10];

    // workspace layout (u16 units):
    //   [0, 4M)       Wt  : 4 x 1024x1024 bf16              (8 MB)
    //   [4M, 16M)     QKV : Q row-major, K packed, V packed (24 MB)
    //                 Q seg reused as Xc after k_attn (Q dead)
    //   [16M, 28M)    Abf : q,k,v bf16 (dead after k_proj)
    //                 reused: Xp = Abf (3 segs of 4M)
    //   [28M, +768KB) Lp  : 3 x 4096x16 f32
    u16*   Wt  = (u16*)d_ws;
    u16*   QKV = Wt + (size_t)4 * 1048576;
    u16*   Abf = QKV + (size_t)3 * 4194304;
    u16*   Xp  = Abf;                         // reuse (Abf dead after k_proj)
    u16*   Xc  = QKV;                         // reuse Q segment (dead after k_attn)
    float* Lp  = (float*)(Abf + (size_t)3 * 4194304);

    k_transw<<<dim3(32, 32, 4), dim3(32, 8), 0, stream>>>(Wq, Wk, Wv, Wo, Wt);
    k_cvt<<<dim3(2048, 1, 3), 256, 0, stream>>>(q, k, v, Abf);
    k_proj<<<dim3(8, 32, 3), 256, 0, stream>>>(Abf, Wt, bq, bk, bv, QKV);
    k_attn<<<dim3(1536), 256, 0, stream>>>(QKV, QKV + (size_t)4194304,
                                           QKV + (size_t)2 * 4194304, Xp, Lp);
    k_combine<<<2048, 256, 0, stream>>>(Xp, Lp, Xc);
    k_gemm_out<<<dim3(8, 32), 256, 0, stream>>>(Xc, Wt + (size_t)3 * 1048576,
                                                bo, (float*)d_out);
}